// Round 15
// baseline (36.083 us; speedup 1.0000x reference)
//
#include <hip/hip_runtime.h>

#define NN 4096
#define FIN 256
#define FOUT 64
#define NH 4
#define CAP 128    // max edges/row; Binomial(4096,0.01) P(>127) ~ 1e-30
#define CPB 1024   // scan blocks (FIRST): 4 rows each, one wave per row
#define MFB 256    // mfma blocks: 64 nodes x 1 head each

typedef __attribute__((ext_vector_type(8))) short bf16x8;
typedef __attribute__((ext_vector_type(4))) float f32x4;

__device__ __forceinline__ unsigned short f2bf(float f) {   // RNE f32->bf16
    unsigned u = __float_as_uint(f);
    u = (u + 0x7fff + ((u >> 16) & 1)) >> 16;
    return (unsigned short)u;
}
__device__ __forceinline__ float bf2f(unsigned short s) {
    return __uint_as_float((unsigned)s << 16);
}

// ---------------------------------------------------------------------------
// K1 (fused; scan blocks first). LDS = 16 KB, scan path = ~40 VGPR,
// __launch_bounds__(256,6) -> target >=24 waves/CU so the adj stream is fed.
//  [0,CPB):    adj (64MB) -> ballot bitmask (2MB). 2 batches of 8 int4.
//  [CPB,+MFB): MFMA hprime, K split in two 128-halves through a 16 KB
//              fragment-linear bfrag. A-frags direct from global h per half.
//              Outputs bf16 h' (hb) + node-major src/dst table (sd).
// ---------------------------------------------------------------------------
__global__ __launch_bounds__(256, 6) void gat_prep(
    const float* __restrict__ h, const int* __restrict__ adj,
    const float* __restrict__ w, const float* __restrict__ a_src,
    const float* __restrict__ a_dst,
    unsigned short* __restrict__ hb, float* __restrict__ sd,
    unsigned long long* __restrict__ bits)
{
    const int b = blockIdx.x, t = threadIdx.x;
    const int wv = t >> 6, lane = t & 63;

    __shared__ bf16x8 bfrag[1024];                          // 16 KB

    if (b < CPB) {
        // ---- scan: one wave owns one row; 8 int4 in flight per batch ----
        const int row = b * 4 + wv;
        const int4* arow = (const int4*)(adj + (size_t)row * NN);
        unsigned long long* brow = bits + (size_t)row * 64;
#pragma unroll
        for (int half = 0; half < 2; ++half) {
            int4 buf[8];
#pragma unroll
            for (int it = 0; it < 8; ++it)
                buf[it] = arow[(half * 8 + it) * 64 + lane];
#pragma unroll
            for (int it = 0; it < 8; ++it) {
                const unsigned long long b0 = __ballot(buf[it].x != 0);
                const unsigned long long b1 = __ballot(buf[it].y != 0);
                const unsigned long long b2 = __ballot(buf[it].z != 0);
                const unsigned long long b3 = __ballot(buf[it].w != 0);
                unsigned long long mk = b0;
                mk = ((lane & 3) == 1) ? b1 : mk;
                mk = ((lane & 3) == 2) ? b2 : mk;
                mk = ((lane & 3) == 3) ? b3 : mk;
                if (lane < 4) brow[(half * 8 + it) * 4 + lane] = mk;
            }
        }
    } else {
        // ---- MFMA hprime, two K-halves through 16 KB LDS ----
        const int b2 = b - CPB;
        const int head = b2 & 3, n0 = (b2 >> 2) * 64;
        const int lrow = lane & 15, lk8 = lane >> 4;
        const float* hrow = h + (size_t)(n0 + wv * 16 + lrow) * FIN + lk8 * 8;

        f32x4 acc[4] = {{0.f,0.f,0.f,0.f},{0.f,0.f,0.f,0.f},
                        {0.f,0.f,0.f,0.f},{0.f,0.f,0.f,0.f}};

#pragma unroll
        for (int kh = 0; kh < 2; ++kh) {
            // A-fragments for this half (8 indep float4 loads)
            bf16x8 a[4];
#pragma unroll
            for (int j = 0; j < 4; ++j) {
                const float* p = hrow + kh * 128 + j * 32;
                const float4 v0 = *(const float4*)(p);
                const float4 v1 = *(const float4*)(p + 4);
                union { bf16x8 v; unsigned short s[8]; } u;
                u.s[0] = f2bf(v0.x); u.s[1] = f2bf(v0.y);
                u.s[2] = f2bf(v0.z); u.s[3] = f2bf(v0.w);
                u.s[4] = f2bf(v1.x); u.s[5] = f2bf(v1.y);
                u.s[6] = f2bf(v1.z); u.s[7] = f2bf(v1.w);
                a[j] = u.v;
            }
            // stage this half of w[head] as fragment-linear granules
            // granule g: lg=g&63, ksl=(g>>6)&3, nt=g>>8;
            // col = nt*16+(lg&15), kbase = kh*128 + ksl*32 + (lg>>4)*8
#pragma unroll
            for (int i = 0; i < 4; ++i) {
                const int g = t + i * 256;
                const int lg = g & 63, ksl = (g >> 6) & 3, nt = g >> 8;
                const int col = nt * 16 + (lg & 15);
                const int kbase = kh * 128 + ksl * 32 + (lg >> 4) * 8;
                const float* wp = w + ((size_t)head * FIN + kbase) * FOUT + col;
                union { bf16x8 v; unsigned short s[8]; } u;
#pragma unroll
                for (int j = 0; j < 8; ++j) u.s[j] = f2bf(wp[j * FOUT]);
                bfrag[g] = u.v;
            }
            __syncthreads();
#pragma unroll
            for (int j = 0; j < 4; ++j)
#pragma unroll
                for (int nt = 0; nt < 4; ++nt)
                    acc[nt] = __builtin_amdgcn_mfma_f32_16x16x32_bf16(
                                  a[j], bfrag[(nt * 4 + j) * 64 + lane], acc[nt], 0, 0, 0);
            __syncthreads();   // bfrag reuse fence (and tail-half no-op)
        }

        // ---- C store (bf16): row m = wv*16 + lk8*4 + r, col = nt*16 + lrow ----
        const int mbase = n0 + wv * 16 + lk8 * 4;
#pragma unroll
        for (int nt = 0; nt < 4; ++nt)
#pragma unroll
            for (int r = 0; r < 4; ++r)
                hb[((size_t)head * NN + mbase + r) * FOUT + nt * 16 + lrow] =
                    f2bf(acc[nt][r]);

        // ---- src/dst logits -> node-major sd table ----
        float as_nt[4], ad_nt[4];
#pragma unroll
        for (int nt = 0; nt < 4; ++nt) {
            as_nt[nt] = a_src[head * FOUT + nt * 16 + lrow];
            ad_nt[nt] = a_dst[head * FOUT + nt * 16 + lrow];
        }
        float psr[4] = {0.f,0.f,0.f,0.f}, pdr[4] = {0.f,0.f,0.f,0.f};
#pragma unroll
        for (int nt = 0; nt < 4; ++nt)
#pragma unroll
            for (int r = 0; r < 4; ++r) {
                psr[r] = fmaf(acc[nt][r], as_nt[nt], psr[r]);
                pdr[r] = fmaf(acc[nt][r], ad_nt[nt], pdr[r]);
            }
#pragma unroll
        for (int r = 0; r < 4; ++r)
#pragma unroll
            for (int off = 1; off <= 8; off <<= 1) {
                psr[r] += __shfl_xor(psr[r], off, 64);
                pdr[r] += __shfl_xor(pdr[r], off, 64);
            }
        if (lrow == 0)
#pragma unroll
            for (int r = 0; r < 4; ++r) {
                sd[(size_t)(mbase + r) * 8 + head]     = psr[r];
                sd[(size_t)(mbase + r) * 8 + 4 + head] = pdr[r];
            }
    }
}

// ---------------------------------------------------------------------------
// K2: attn. Block = row i; wave 0 decodes mask into LDS edge list; scores
// via one float4 per edge (all 4 heads) from sd; per-head softmax (wave =
// head); 8-deep batched gather from bf16 hb (2 MB, L2-resident).
// ---------------------------------------------------------------------------
__global__ __launch_bounds__(256) void gat_attn(
    const unsigned long long* __restrict__ bits,
    const unsigned short* __restrict__ hb, const float* __restrict__ sd,
    const float* __restrict__ bias, float* __restrict__ out)
{
    const int i = blockIdx.x, t = threadIdx.x, wv = t >> 6, lane = t & 63;

    __shared__ int   idx_l[CAP];
    __shared__ float sc[NH][CAP];
    __shared__ int   cnt;
    __shared__ float inv_sum[NH];

    if (wv == 0) {
        unsigned long long m = bits[(size_t)i * 64 + lane];
        const int c = __popcll(m);
        int pre = c;
#pragma unroll
        for (int off = 1; off < 64; off <<= 1) {
            const int nb = __shfl_up(pre, off, 64);
            if (lane >= off) pre += nb;
        }
        int p = pre - c;
        const int cb = (lane >> 2) * 256 + (lane & 3);
        while (m) {
            const int bpos = __ffsll((unsigned long long)m) - 1;
            if (p < CAP) idx_l[p] = cb + 4 * bpos;
            ++p;
            m &= m - 1;
        }
        if (lane == 63) cnt = pre;
    }
    __syncthreads();

    const int count = min(cnt, CAP);
    const int cpad  = (count + 7) & ~7;

    if (t < count) {
        const int j = idx_l[t];
        const float4 sv = *(const float4*)(sd + (size_t)i * 8);       // src, 4 heads
        const float4 dv = *(const float4*)(sd + (size_t)j * 8 + 4);   // dst, 4 heads
        const float s0 = sv.x + dv.x, s1 = sv.y + dv.y;
        const float s2 = sv.z + dv.z, s3 = sv.w + dv.w;
        sc[0][t] = (s0 >= 0.f) ? s0 : 0.2f * s0;
        sc[1][t] = (s1 >= 0.f) ? s1 : 0.2f * s1;
        sc[2][t] = (s2 >= 0.f) ? s2 : 0.2f * s2;
        sc[3][t] = (s3 >= 0.f) ? s3 : 0.2f * s3;
    } else if (t < cpad) {
        idx_l[t] = 0;
#pragma unroll
        for (int hh = 0; hh < NH; ++hh) sc[hh][t] = 0.f;
    }
    __syncthreads();

    {
        float m = -3.4e38f;
        for (int p = lane; p < count; p += 64) m = fmaxf(m, sc[wv][p]);
#pragma unroll
        for (int off = 32; off >= 1; off >>= 1) m = fmaxf(m, __shfl_xor(m, off, 64));
        float e = 0.f;
        for (int p = lane; p < count; p += 64) {
            const float v = __expf(sc[wv][p] - m);
            sc[wv][p] = v;
            e += v;
        }
#pragma unroll
        for (int off = 32; off >= 1; off >>= 1) e += __shfl_xor(e, off, 64);
        if (lane == 0) inv_sum[wv] = 1.f / e;
    }
    __syncthreads();

    // gather from bf16 hb (128 B/row coalesced), 8 rows in flight
    float accv = 0.f;
    const unsigned short* hp = hb + (size_t)(wv * NN) * FOUT + lane;
    for (int p0 = 0; p0 < cpad; p0 += 8) {
        int jj[8]; unsigned short vv[8]; float ww[8];
#pragma unroll
        for (int k = 0; k < 8; ++k) jj[k] = idx_l[p0 + k];
#pragma unroll
        for (int k = 0; k < 8; ++k) vv[k] = hp[(size_t)jj[k] * FOUT];
#pragma unroll
        for (int k = 0; k < 8; ++k) ww[k] = sc[wv][p0 + k];
#pragma unroll
        for (int k = 0; k < 8; ++k) accv = fmaf(ww[k], bf2f(vv[k]), accv);
    }
    out[(size_t)i * (NH * FOUT) + wv * FOUT + lane] = accv * inv_sum[wv] + bias[lane];
}

extern "C" void kernel_launch(void* const* d_in, const int* in_sizes, int n_in,
                              void* d_out, int out_size, void* d_ws, size_t ws_size,
                              hipStream_t stream) {
    const float* h     = (const float*)d_in[0];
    const int*   adj   = (const int*)d_in[1];
    const float* w     = (const float*)d_in[2];
    const float* a_src = (const float*)d_in[3];
    const float* a_dst = (const float*)d_in[4];
    const float* bias  = (const float*)d_in[5];
    float* out = (float*)d_out;

    unsigned short* hb = (unsigned short*)d_ws;                 // 2 MB bf16 h'
    float* sd          = (float*)(hb + (size_t)NH * NN * FOUT); // NN*8 floats
    unsigned long long* bits = (unsigned long long*)(sd + (size_t)NN * 8); // 2 MB

    gat_prep<<<CPB + MFB, 256, 0, stream>>>(h, adj, w, a_src, a_dst, hb, sd, bits);
    gat_attn<<<NN, 256, 0, stream>>>(bits, hb, sd, bias, out);
}

// Round 16
// 35.275 us; speedup vs baseline: 1.0229x; 1.0229x over previous
//
#include <hip/hip_runtime.h>

#define NN 4096
#define FIN 256
#define FOUT 64
#define NH 4
#define CAP 128    // max edges/row; Binomial(4096,0.01) P(>127) ~ 1e-30

typedef __attribute__((ext_vector_type(8))) short bf16x8;
typedef __attribute__((ext_vector_type(4))) float f32x4;

__device__ __forceinline__ unsigned short f2bf(float f) {   // RNE f32->bf16
    unsigned u = __float_as_uint(f);
    u = (u + 0x7fff + ((u >> 16) & 1)) >> 16;
    return (unsigned short)u;
}
__device__ __forceinline__ float bf2f(unsigned short s) {
    return __uint_as_float((unsigned)s << 16);
}
// popcount of mask restricted to lanes strictly below mine
__device__ __forceinline__ int mbcnt64(unsigned long long m) {
    return __builtin_amdgcn_mbcnt_hi((unsigned)(m >> 32),
           __builtin_amdgcn_mbcnt_lo((unsigned)m, 0));
}

// ---------------------------------------------------------------------------
// K1: MFMA hprime. Block = 64 nodes x 1 head (256 blocks). A-frags direct
// from global h (in-reg bf16 convert); w staged fragment-linear in LDS
// (32 KB, conflict-free b128). 32 MFMA/wave. Outputs: hb (bf16 h', 2 MB,
// L2-resident for K2's gather) + sd (node-major src/dst float4 pairs).
// ---------------------------------------------------------------------------
__global__ __launch_bounds__(256) void gat_mfma(
    const float* __restrict__ h, const float* __restrict__ w,
    const float* __restrict__ a_src, const float* __restrict__ a_dst,
    unsigned short* __restrict__ hb, float* __restrict__ sd)
{
    const int b = blockIdx.x, t = threadIdx.x;
    const int wv = t >> 6, lane = t & 63;
    const int head = b & 3, n0 = (b >> 2) * 64;
    const int lrow = lane & 15, lk8 = lane >> 4;

    __shared__ bf16x8 bfrag[2048];                          // 32 KB

    // ---- A-fragments straight from global h (16 indep float4 loads) ----
    const float* hrow = h + (size_t)(n0 + wv * 16 + lrow) * FIN + lk8 * 8;
    bf16x8 a[8];
#pragma unroll
    for (int ks = 0; ks < 8; ++ks) {
        const float4 v0 = *(const float4*)(hrow + ks * 32);
        const float4 v1 = *(const float4*)(hrow + ks * 32 + 4);
        union { bf16x8 v; unsigned short s[8]; } u;
        u.s[0] = f2bf(v0.x); u.s[1] = f2bf(v0.y);
        u.s[2] = f2bf(v0.z); u.s[3] = f2bf(v0.w);
        u.s[4] = f2bf(v1.x); u.s[5] = f2bf(v1.y);
        u.s[6] = f2bf(v1.z); u.s[7] = f2bf(v1.w);
        a[ks] = u.v;
    }

    // ---- stage w[head] as fragment-linear granules ----
    // granule g: lg=g&63, ks=(g>>6)&7, nt=g>>9; col = nt*16+(lg&15),
    // kbase = ks*32 + (lg>>4)*8
#pragma unroll
    for (int i = 0; i < 8; ++i) {
        const int g = t + i * 256;
        const int lg = g & 63, ks = (g >> 6) & 7, nt = g >> 9;
        const int col = nt * 16 + (lg & 15);
        const int kbase = ks * 32 + (lg >> 4) * 8;
        const float* wp = w + ((size_t)head * FIN + kbase) * FOUT + col;
        union { bf16x8 v; unsigned short s[8]; } u;
#pragma unroll
        for (int j = 0; j < 8; ++j) u.s[j] = f2bf(wp[j * FOUT]);
        bfrag[g] = u.v;
    }
    __syncthreads();

    f32x4 acc[4] = {{0.f,0.f,0.f,0.f},{0.f,0.f,0.f,0.f},
                    {0.f,0.f,0.f,0.f},{0.f,0.f,0.f,0.f}};
#pragma unroll
    for (int ks = 0; ks < 8; ++ks) {
#pragma unroll
        for (int nt = 0; nt < 4; ++nt)
            acc[nt] = __builtin_amdgcn_mfma_f32_16x16x32_bf16(
                          a[ks], bfrag[(nt * 8 + ks) * 64 + lane], acc[nt], 0, 0, 0);
    }

    // ---- C store (bf16): row m = wv*16 + lk8*4 + r, col = nt*16 + lrow ----
    const int mbase = n0 + wv * 16 + lk8 * 4;
#pragma unroll
    for (int nt = 0; nt < 4; ++nt)
#pragma unroll
        for (int r = 0; r < 4; ++r)
            hb[((size_t)head * NN + mbase + r) * FOUT + nt * 16 + lrow] =
                f2bf(acc[nt][r]);

    // ---- src/dst logits -> node-major sd table ----
    float as_nt[4], ad_nt[4];
#pragma unroll
    for (int nt = 0; nt < 4; ++nt) {
        as_nt[nt] = a_src[head * FOUT + nt * 16 + lrow];
        ad_nt[nt] = a_dst[head * FOUT + nt * 16 + lrow];
    }
    float psr[4] = {0.f,0.f,0.f,0.f}, pdr[4] = {0.f,0.f,0.f,0.f};
#pragma unroll
    for (int nt = 0; nt < 4; ++nt)
#pragma unroll
        for (int r = 0; r < 4; ++r) {
            psr[r] = fmaf(acc[nt][r], as_nt[nt], psr[r]);
            pdr[r] = fmaf(acc[nt][r], ad_nt[nt], pdr[r]);
        }
#pragma unroll
    for (int r = 0; r < 4; ++r)
#pragma unroll
        for (int off = 1; off <= 8; off <<= 1) {
            psr[r] += __shfl_xor(psr[r], off, 64);
            pdr[r] += __shfl_xor(pdr[r], off, 64);
        }
    if (lrow == 0)
#pragma unroll
        for (int r = 0; r < 4; ++r) {
            sd[(size_t)(mbase + r) * 8 + head]     = psr[r];
            sd[(size_t)(mbase + r) * 8 + 4 + head] = pdr[r];
        }
}

// ---------------------------------------------------------------------------
// K2: fused scan+attn (no bits intermediate, no third launch). Block = row i.
// Reads its own 16 KB adj row coalesced (wave wv owns int4 range
// [wv*256, wv*256+256)), ballot+chunk-prefix compacts edge columns into LDS
// in deterministic order, then: scores via one float4 per edge (all 4 heads)
// from sd -> per-head softmax (wave = head) -> 8-deep bf16 gather from hb.
// ---------------------------------------------------------------------------
__global__ __launch_bounds__(256) void gat_attn(
    const int* __restrict__ adj, const unsigned short* __restrict__ hb,
    const float* __restrict__ sd, const float* __restrict__ bias,
    float* __restrict__ out)
{
    const int i = blockIdx.x, t = threadIdx.x, wv = t >> 6, lane = t & 63;

    __shared__ int   idx_l[CAP];
    __shared__ float sc[NH][CAP];
    __shared__ int   ccnt[16];
    __shared__ float inv_sum[NH];

    // Phase A: issue my 4 int4 loads of the row back-to-back
    const int4* arow = (const int4*)(adj + (size_t)i * NN);
    int4 a[4];
#pragma unroll
    for (int it = 0; it < 4; ++it) a[it] = arow[wv * 256 + it * 64 + lane];

    // Phase B: ballots -> within-chunk offset + per-chunk count
    int myoff[4];
#pragma unroll
    for (int it = 0; it < 4; ++it) {
        const unsigned long long b0 = __ballot(a[it].x != 0);
        const unsigned long long b1 = __ballot(a[it].y != 0);
        const unsigned long long b2 = __ballot(a[it].z != 0);
        const unsigned long long b3 = __ballot(a[it].w != 0);
        myoff[it] = mbcnt64(b0) + mbcnt64(b1) + mbcnt64(b2) + mbcnt64(b3);
        if (lane == 0)
            ccnt[wv * 4 + it] = __popcll(b0) + __popcll(b1) +
                                __popcll(b2) + __popcll(b3);
    }
    __syncthreads();

    // chunk-prefix (16 chunks) -> deterministic layout
    int cb[4];
    int s = 0;
#pragma unroll
    for (int k = 0; k < 16; ++k) {
        if ((k >> 2) == wv) cb[k & 3] = s;
        s += ccnt[k];
    }
    const int count = min(s, CAP);
    const int cpad  = (count + 7) & ~7;

    // Phase C: scatter edge columns into LDS
#pragma unroll
    for (int it = 0; it < 4; ++it) {
        int p = cb[it] + myoff[it];
        const int col0 = (wv * 256 + it * 64 + lane) * 4;
        if (a[it].x) { if (p < CAP) idx_l[p] = col0;     ++p; }
        if (a[it].y) { if (p < CAP) idx_l[p] = col0 + 1; ++p; }
        if (a[it].z) { if (p < CAP) idx_l[p] = col0 + 2; ++p; }
        if (a[it].w) { if (p < CAP) idx_l[p] = col0 + 3; ++p; }
    }
    __syncthreads();

    // scores: one float4 pair per edge covers all 4 heads
    if (t < count) {
        const int j = idx_l[t];
        const float4 sv = *(const float4*)(sd + (size_t)i * 8);       // src, 4 heads
        const float4 dv = *(const float4*)(sd + (size_t)j * 8 + 4);   // dst, 4 heads
        const float s0 = sv.x + dv.x, s1 = sv.y + dv.y;
        const float s2 = sv.z + dv.z, s3 = sv.w + dv.w;
        sc[0][t] = (s0 >= 0.f) ? s0 : 0.2f * s0;
        sc[1][t] = (s1 >= 0.f) ? s1 : 0.2f * s1;
        sc[2][t] = (s2 >= 0.f) ? s2 : 0.2f * s2;
        sc[3][t] = (s3 >= 0.f) ? s3 : 0.2f * s3;
    } else if (t < cpad) {
        idx_l[t] = 0;
#pragma unroll
        for (int hh = 0; hh < NH; ++hh) sc[hh][t] = 0.f;
    }
    __syncthreads();

    // per-head softmax (wave = head); padded entries stay exactly 0
    {
        float m = -3.4e38f;
        for (int p = lane; p < count; p += 64) m = fmaxf(m, sc[wv][p]);
#pragma unroll
        for (int off = 32; off >= 1; off >>= 1) m = fmaxf(m, __shfl_xor(m, off, 64));
        float e = 0.f;
        for (int p = lane; p < count; p += 64) {
            const float v = __expf(sc[wv][p] - m);
            sc[wv][p] = v;
            e += v;
        }
#pragma unroll
        for (int off = 32; off >= 1; off >>= 1) e += __shfl_xor(e, off, 64);
        if (lane == 0) inv_sum[wv] = 1.f / e;
    }
    __syncthreads();

    // gather from bf16 hb (128 B/row coalesced), 8 rows in flight
    float accv = 0.f;
    const unsigned short* hp = hb + (size_t)(wv * NN) * FOUT + lane;
    for (int p0 = 0; p0 < cpad; p0 += 8) {
        int jj[8]; unsigned short vv[8]; float ww[8];
#pragma unroll
        for (int k = 0; k < 8; ++k) jj[k] = idx_l[p0 + k];
#pragma unroll
        for (int k = 0; k < 8; ++k) vv[k] = hp[(size_t)jj[k] * FOUT];
#pragma unroll
        for (int k = 0; k < 8; ++k) ww[k] = sc[wv][p0 + k];
#pragma unroll
        for (int k = 0; k < 8; ++k) accv = fmaf(ww[k], bf2f(vv[k]), accv);
    }
    out[(size_t)i * (NH * FOUT) + wv * FOUT + lane] = accv * inv_sum[wv] + bias[lane];
}

extern "C" void kernel_launch(void* const* d_in, const int* in_sizes, int n_in,
                              void* d_out, int out_size, void* d_ws, size_t ws_size,
                              hipStream_t stream) {
    const float* h     = (const float*)d_in[0];
    const int*   adj   = (const int*)d_in[1];
    const float* w     = (const float*)d_in[2];
    const float* a_src = (const float*)d_in[3];
    const float* a_dst = (const float*)d_in[4];
    const float* bias  = (const float*)d_in[5];
    float* out = (float*)d_out;

    unsigned short* hb = (unsigned short*)d_ws;                 // 2 MB bf16 h'
    float* sd          = (float*)(hb + (size_t)NH * NN * FOUT); // NN*8 floats

    gat_mfma<<<256, 256, 0, stream>>>(h, w, a_src, a_dst, hb, sd);
    gat_attn<<<NN, 256, 0, stream>>>(adj, hb, sd, bias, out);
}